// Round 1
// baseline (104.886 us; speedup 1.0000x reference)
//
#include <hip/hip_runtime.h>

// y[b,t] = tanh(b2[t] + sum_h W2[t,h] * relu(x[b,t]*W1[t,h] + b1[t,h]))
// B=262144, T=30, H=20. Memory-bound elementwise: 63 MB traffic -> ~10us floor.
//
// Layout strategy: one thread per row b (30 consecutive elements). The t-loop
// index is wave-uniform so all param loads (W1/b1/W2/b2) should compile to
// s_load (scalar cache) -- zero per-element cost. x is transposed through a
// +1-padded LDS tile so global loads/stores stay fully coalesced while each
// thread reads its own row from LDS (stride 31 = odd -> no bank conflicts).

#define TT 30
#define HH 20
#define BLK 256
#define LDS_STRIDE (TT + 1)  // 31, odd -> conflict-free row access

__global__ __launch_bounds__(BLK) void rnn_mlp_kernel(
    const float* __restrict__ x,
    const float* __restrict__ W1,   // [T][H]
    const float* __restrict__ b1,   // [T][H]
    const float* __restrict__ W2,   // [T][H] (T,1,H flattened)
    const float* __restrict__ b2,   // [T]
    float* __restrict__ y)
{
    __shared__ float xs[BLK * LDS_STRIDE];  // 256*31*4 = 31.75 KB -> 5 blocks/CU
    const int tid = threadIdx.x;
    const long long base = (long long)blockIdx.x * (BLK * TT);

    // ---- Stage x tile: coalesced global dword loads -> padded LDS rows ----
    #pragma unroll
    for (int k = 0; k < TT; ++k) {
        int f = k * BLK + tid;          // 0..7679, lane-consecutive
        int row = f / TT;               // magic-mul div by 30
        int col = f - row * TT;
        xs[row * LDS_STRIDE + col] = x[base + f];
    }
    __syncthreads();

    float* myrow = &xs[tid * LDS_STRIDE];

    // ---- Compute: each thread owns one row b, loops t (wave-uniform) ----
    #pragma unroll 1   // keep SGPR pressure bounded (61 uniform params/iter)
    for (int t = 0; t < TT; ++t) {
        float xv = myrow[t];
        float acc = b2[t];
        #pragma unroll
        for (int h = 0; h < HH; ++h) {
            float a = fmaf(xv, W1[t * HH + h], b1[t * HH + h]);
            a = fmaxf(a, 0.0f);
            acc = fmaf(a, W2[t * HH + h], acc);
        }
        // tanh(acc) = 1 - 2/(exp(2*acc)+1); saturates to +/-1 correctly.
        float e = __expf(2.0f * acc);
        float r = __builtin_amdgcn_rcpf(e + 1.0f);
        myrow[t] = fmaf(-2.0f, r, 1.0f);
    }
    __syncthreads();

    // ---- Write out: padded LDS rows -> coalesced global dword stores ----
    #pragma unroll
    for (int k = 0; k < TT; ++k) {
        int f = k * BLK + tid;
        int row = f / TT;
        int col = f - row * TT;
        y[base + f] = xs[row * LDS_STRIDE + col];
    }
}

extern "C" void kernel_launch(void* const* d_in, const int* in_sizes, int n_in,
                              void* d_out, int out_size, void* d_ws, size_t ws_size,
                              hipStream_t stream) {
    const float* x  = (const float*)d_in[0];   // [B,T,1]
    const float* W1 = (const float*)d_in[1];   // [T,H,1]
    const float* b1 = (const float*)d_in[2];   // [T,H]
    const float* W2 = (const float*)d_in[3];   // [T,1,H]
    const float* b2 = (const float*)d_in[4];   // [T,1]
    float* y = (float*)d_out;

    const int B = in_sizes[0] / TT;            // 262144
    const int grid = B / BLK;                  // 1024 (B divisible by 256)
    rnn_mlp_kernel<<<grid, BLK, 0, stream>>>(x, W1, b1, W2, b2, y);
}

// Round 2
// 102.859 us; speedup vs baseline: 1.0197x; 1.0197x over previous
//
#include <hip/hip_runtime.h>

// y[b,t] = tanh(b2[t] + sum_h W2[t,h] * relu(x[b,t]*W1[t,h] + b1[t,h]))
// B=262144, T=30, H=20. Memory-bound: 63 MB HBM traffic -> ~10us floor.
//
// R2 changes vs R1 (104.9us):
//  - Flat (unpermuted) LDS staging with float2 coalesced global loads: kills
//    all per-element index math (magic-div by 30) and halves VMEM instrs.
//    Compute phase reads xs[tid*30+t]: lane-stride 30 -> only 4-way bank
//    aliasing on a single ds_read per t-iter (negligible, ~1.6x on ~2% of instrs).
//  - Params read as float4 (rows are 80B-offset = 16B-aligned): 16 loads per
//    t-iter instead of 41. Addresses are wave-uniform -> s_load or single
//    L1-resident transaction per instr either way.

#define TT 30
#define HH 20
#define BLK 256
#define ROWS_PER_BLK BLK
#define TILE (ROWS_PER_BLK * TT)        // 7680 floats = 30 KB LDS

__global__ __launch_bounds__(BLK) void rnn_mlp_kernel(
    const float* __restrict__ x,
    const float4* __restrict__ W1v,   // [T][5] float4 (rows 16B-aligned: 80B pitch)
    const float4* __restrict__ b1v,   // [T][5]
    const float4* __restrict__ W2v,   // [T][5]
    const float* __restrict__ b2,     // [T]
    float* __restrict__ y)
{
    __shared__ float xs[TILE];
    const int tid = threadIdx.x;
    const long long base = (long long)blockIdx.x * TILE;

    // ---- Stage tile flat: 15 coalesced float2 loads, no index math ----
    const float2* __restrict__ xin = (const float2*)(x + base);
    float2* __restrict__ xs2 = (float2*)xs;
    #pragma unroll
    for (int k = 0; k < TILE / 2 / BLK; ++k)        // 15 iters
        xs2[k * BLK + tid] = xin[k * BLK + tid];
    __syncthreads();

    float* myrow = &xs[tid * TT];

    // ---- Compute: one row b per thread; t is wave-uniform ----
    #pragma unroll 1
    for (int t = 0; t < TT; ++t) {
        const float xv = myrow[t];
        float acc = b2[t];
        #pragma unroll
        for (int i = 0; i < HH / 4; ++i) {          // 5 float4 groups
            const float4 w1 = W1v[t * 5 + i];
            const float4 bb = b1v[t * 5 + i];
            const float4 w2 = W2v[t * 5 + i];
            acc = fmaf(fmaxf(fmaf(xv, w1.x, bb.x), 0.0f), w2.x, acc);
            acc = fmaf(fmaxf(fmaf(xv, w1.y, bb.y), 0.0f), w2.y, acc);
            acc = fmaf(fmaxf(fmaf(xv, w1.z, bb.z), 0.0f), w2.z, acc);
            acc = fmaf(fmaxf(fmaf(xv, w1.w, bb.w), 0.0f), w2.w, acc);
        }
        // tanh(a) = 1 - 2/(exp(2a)+1); saturates correctly at +/-1.
        const float e = __expf(2.0f * acc);
        const float r = __builtin_amdgcn_rcpf(e + 1.0f);
        myrow[t] = fmaf(-2.0f, r, 1.0f);
    }
    __syncthreads();

    // ---- Write out flat: 15 coalesced float2 stores ----
    float2* __restrict__ yout = (float2*)(y + base);
    #pragma unroll
    for (int k = 0; k < TILE / 2 / BLK; ++k)
        yout[k * BLK + tid] = xs2[k * BLK + tid];
}

extern "C" void kernel_launch(void* const* d_in, const int* in_sizes, int n_in,
                              void* d_out, int out_size, void* d_ws, size_t ws_size,
                              hipStream_t stream) {
    const float* x  = (const float*)d_in[0];   // [B,T,1]
    const float* W1 = (const float*)d_in[1];   // [T,H,1]
    const float* b1 = (const float*)d_in[2];   // [T,H]
    const float* W2 = (const float*)d_in[3];   // [T,1,H]
    const float* b2 = (const float*)d_in[4];   // [T,1]
    float* y = (float*)d_out;

    const int B = in_sizes[0] / TT;            // 262144
    const int grid = B / ROWS_PER_BLK;         // 1024
    rnn_mlp_kernel<<<grid, BLK, 0, stream>>>(
        x, (const float4*)W1, (const float4*)b1, (const float4*)W2, b2, y);
}

// Round 3
// 94.543 us; speedup vs baseline: 1.1094x; 1.0880x over previous
//
#include <hip/hip_runtime.h>

// y[b,t] = tanh(b2[t] + sum_h W2[t,h] * relu(x[b,t]*W1[t,h] + b1[t,h]))
// B=262144, T=30, H=20. Memory-bound: 63 MB HBM traffic -> ~10us kernel floor.
//
// R3: fixed-t threads. Grid-stride = 245760 elements (divisible by 30), so
// each thread's t = g % 30 is invariant -> its 61 params load ONCE into VGPRs
// (L1-resident gather, amortized over 32 elements). Main loop is pure
// coalesced dword load -> 60 FMA + fast tanh -> coalesced dword store.
// No LDS, no barriers, no in-loop uniform-load stalls (the R2 suspect).

#define TT 30
#define HH 20
#define BLK 256
#define EPT 32                      // elements per thread
#define BATCH 8                     // loads in flight per thread

__global__ __launch_bounds__(BLK) void rnn_mlp_kernel(
    const float* __restrict__ x,
    const float* __restrict__ W1,   // [T][H]
    const float* __restrict__ b1,   // [T][H]
    const float* __restrict__ W2,   // [T][H]
    const float* __restrict__ b2,   // [T]
    float* __restrict__ y,
    int stride)                     // total threads; stride % 30 == 0
{
    const int g = blockIdx.x * BLK + threadIdx.x;
    const int t = g % TT;           // invariant across the grid-stride loop

    // ---- Load this thread's 61 params into VGPRs (params are 7.3 KB -> L1) ----
    const float4* w1v = (const float4*)(W1 + t * HH);
    const float4* b1v = (const float4*)(b1 + t * HH);
    const float4* w2v = (const float4*)(W2 + t * HH);
    float4 w1[5], bb[5], w2[5];
    #pragma unroll
    for (int i = 0; i < 5; ++i) { w1[i] = w1v[i]; bb[i] = b1v[i]; w2[i] = w2v[i]; }
    const float bias2 = b2[t];

    const float* w1f = (const float*)w1;
    const float* bbf = (const float*)bb;
    const float* w2f = (const float*)w2;

    // ---- Main loop: BATCH loads in flight, then compute+store the batch ----
    #pragma unroll 1
    for (int k = 0; k < EPT; k += BATCH) {
        float xv[BATCH];
        #pragma unroll
        for (int j = 0; j < BATCH; ++j)
            xv[j] = x[g + (long long)(k + j) * stride];

        #pragma unroll
        for (int j = 0; j < BATCH; ++j) {
            float acc = bias2;
            #pragma unroll
            for (int h = 0; h < HH; ++h) {
                float a = fmaf(xv[j], w1f[h], bbf[h]);
                acc = fmaf(fmaxf(a, 0.0f), w2f[h], acc);
            }
            // tanh(a) = 1 - 2/(exp(2a)+1); saturates correctly at +/-1.
            float e = __expf(2.0f * acc);
            float r = __builtin_amdgcn_rcpf(e + 1.0f);
            y[g + (long long)(k + j) * stride] = fmaf(-2.0f, r, 1.0f);
        }
    }
}

extern "C" void kernel_launch(void* const* d_in, const int* in_sizes, int n_in,
                              void* d_out, int out_size, void* d_ws, size_t ws_size,
                              hipStream_t stream) {
    const float* x  = (const float*)d_in[0];   // [B,T,1]
    const float* W1 = (const float*)d_in[1];   // [T,H,1]
    const float* b1 = (const float*)d_in[2];   // [T,H]
    const float* W2 = (const float*)d_in[3];   // [T,1,H]
    const float* b2 = (const float*)d_in[4];   // [T,1]
    float* y = (float*)d_out;

    const int n = in_sizes[0];                 // 7864320 = 245760 * 32
    const int threads = n / EPT;               // 245760; % 30 == 0 and % 256 == 0
    const int grid = threads / BLK;            // 960
    rnn_mlp_kernel<<<grid, BLK, 0, stream>>>(x, W1, b1, W2, b2, y, threads);
}